// Round 18
// baseline (1096.327 us; speedup 1.0000x reference)
//
#include <hip/hip_runtime.h>

#define T_STEPS 4
#define BATCH   8
#define C_IN    64
#define C_OUT   64
#define HH      128
#define WW      128
#define TH      8           // block tile height (2 wave-strips of 4)
#define TW      16
#define ROWS    (TH + 2)    // 10
#define COLS    18          // staged columns (halo)
#define RLEN    20          // padded row pitch (words): 51200 B LDS -> 3 blocks/CU

// f32 rounding of math.exp(-0.5)
#define DECAY_F32 0.6065306597126334f

// Weight re-layout: w[co][ci][ky][kx] -> wt[j][ci][co], j = ky*3+kx
__global__ void wt_build_kernel(const float* __restrict__ w, float* __restrict__ wt) {
    int tid = blockIdx.x * blockDim.x + threadIdx.x;
    if (tid >= 9 * C_IN * C_OUT) return;
    int co = tid & 63;
    int ci = (tid >> 6) & 63;
    int j  = tid >> 12;
    wt[tid] = w[(co * C_IN + ci) * 9 + j];
}

// Exact replica of the reference f32 arithmetic (probe-verified variant A):
// per output: seq FMA chain over (ky,kx, ci-innermost); cb = acc+bias;
// vt = v*DECAY + cb (separate rounded mul/add); spike = vt>1; soft reset.
//
// r12 structure (the measured-best TAP: 16 co/lane, single ds_read_b32 per
// (tap,ci) in the conflict-light pitch pattern, SGPR-broadcast weights via
// wave-uniform s_load) with RLEN 24->20: LDS 61440->51200 B so THREE blocks
// fit per CU (24 waves/CU, independently-barriered -> staging phases of one
// block overlap compute of the others). Read banks go <=3-way on some lanes
// (~1.3x on the LDS pipe) but LDS has >=8x headroom vs the 32-cyc FMA bursts.
__global__ __launch_bounds__(512, 6) void snn_exact_kernel(
    const float* __restrict__ x,    // [T,B,C_IN,H,W]
    const float* __restrict__ wt,   // [9][C_IN][C_OUT]
    const float* __restrict__ bias, // [C_OUT]
    float* __restrict__ out)        // [T,B,C_OUT,H,W]
{
    __shared__ __align__(16) float sx[C_IN][ROWS][RLEN];   // 51200 B

    const int tid  = threadIdx.x;
    const int wid  = __builtin_amdgcn_readfirstlane(tid >> 6); // 0..7 (SGPR)
    const int lane = tid & 63;
    const int y    = lane & 3;          // 0..3 within strip
    const int xcol = lane >> 2;         // 0..15
    const int sy   = (wid >> 2) << 2;   // strip base: 0 or 4
    const int cob  = (wid & 3) << 4;    // wave's co base: 0,16,32,48
    const int b    = blockIdx.z;
    const int gy0  = blockIdx.y * TH;
    const int gx0  = blockIdx.x * TW;

    const float* bp = bias + cob;       // wave-uniform -> SGPR

    float v[16];
#pragma unroll
    for (int o = 0; o < 16; ++o) v[o] = 0.0f;

    for (int t = 0; t < T_STEPS; ++t) {
        __syncthreads();  // prior t's reads done before overwrite
        const float* xsrc = x + ((size_t)(t * BATCH + b) * C_IN) * (HH * WW);
        for (int e = tid; e < C_IN * ROWS * COLS; e += 512) {
            int ci  = e / (ROWS * COLS);
            int rem = e - ci * (ROWS * COLS);
            int row = rem / COLS;
            int col = rem - row * COLS;
            int gy  = gy0 + row - 1;
            int gx  = gx0 + col - 1;
            float val = 0.0f;
            if ((unsigned)gy < (unsigned)HH && (unsigned)gx < (unsigned)WW)
                val = xsrc[ci * (HH * WW) + gy * WW + gx];
            sx[ci][row][col] = val;
        }
        __syncthreads();

        float acc[16];
#pragma unroll
        for (int o = 0; o < 16; ++o) acc[o] = 0.0f;

// One conv tap: ci 0..63 sequential (exact chain order). One ds_read_b32 per
// ci, 16 FMAs with SGPR-broadcast weights (wave-uniform s_load_dwordx16).
#define TAP(KY, KX)                                                                   \
        {                                                                             \
            const float* wj = wt + ((KY) * 3 + (KX)) * (C_IN * C_OUT) + cob;          \
            _Pragma("unroll 4")                                                       \
            for (int ci = 0; ci < C_IN; ++ci) {                                       \
                const float xv = sx[ci][sy + y + (KY)][xcol + (KX)];                  \
                const float* wp = wj + (ci << 6);                                     \
                _Pragma("unroll")                                                     \
                for (int o = 0; o < 16; ++o)                                          \
                    acc[o] = fmaf(xv, wp[o], acc[o]);                                 \
            }                                                                         \
        }

        TAP(0, 0) TAP(0, 1) TAP(0, 2)
        TAP(1, 0) TAP(1, 1) TAP(1, 2)
        TAP(2, 0) TAP(2, 1) TAP(2, 2)
#undef TAP

        // ---- LIF update (exact f32 op sequence) + spike store ----
        float* obase = out + ((size_t)(t * BATCH + b) * C_OUT + cob) * (HH * WW)
                     + (gy0 + sy + y) * WW + gx0 + xcol;
#pragma unroll
        for (int o = 0; o < 16; ++o) {
            float cb = __fadd_rn(acc[o], bp[o]);                  // conv + bias (SGPR)
            float vt = __fadd_rn(__fmul_rn(v[o], DECAY_F32), cb); // v*DECAY + cb
            bool fire = vt > 1.0f;
            v[o] = fire ? 0.0f : vt;                              // soft reset
            obase[(size_t)o * (HH * WW)] = fire ? 1.0f : 0.0f;
        }
    }
}

extern "C" void kernel_launch(void* const* d_in, const int* in_sizes, int n_in,
                              void* d_out, int out_size, void* d_ws, size_t ws_size,
                              hipStream_t stream) {
    const float* x    = (const float*)d_in[0];
    const float* w    = (const float*)d_in[1];
    const float* bias = (const float*)d_in[2];
    float* out = (float*)d_out;
    float* wt  = (float*)d_ws;   // 9*64*64*4 = 147456 bytes

    hipLaunchKernelGGL(wt_build_kernel, dim3((9 * C_IN * C_OUT + 255) / 256), dim3(256), 0, stream, w, wt);
    hipLaunchKernelGGL(snn_exact_kernel, dim3(WW / TW, HH / TH, BATCH), dim3(512), 0, stream,
                       x, wt, bias, out);
}

// Round 19
// 479.989 us; speedup vs baseline: 2.2841x; 2.2841x over previous
//
#include <hip/hip_runtime.h>

#define T_STEPS 4
#define BATCH   8
#define C_IN    64
#define C_OUT   64
#define HH      128
#define WW      128
#define TH      8           // block tile height (2 wave-strips of 4)
#define TW      16
#define ROWS    (TH + 2)    // 10
#define COLS    18          // staged columns (halo)
#define RLEN    24          // padded row pitch (words) -> measured-conflict-free b32 pattern

// f32 rounding of math.exp(-0.5)
#define DECAY_F32 0.6065306597126334f

// Weight re-layout: w[co][ci][ky][kx] -> wt[j][ci][co], j = ky*3+kx
__global__ void wt_build_kernel(const float* __restrict__ w, float* __restrict__ wt) {
    int tid = blockIdx.x * blockDim.x + threadIdx.x;
    if (tid >= 9 * C_IN * C_OUT) return;
    int co = tid & 63;
    int ci = (tid >> 6) & 63;
    int j  = tid >> 12;
    wt[tid] = w[(co * C_IN + ci) * 9 + j];
}

// Exact replica of the reference f32 arithmetic (probe-verified variant A):
// per output: seq FMA chain over (ky,kx, ci-innermost); cb = acc+bias;
// vt = v*DECAY + cb (separate rounded mul/add); spike = vt>1; soft reset.
//
// This is the measured-best r12 configuration, unchanged: 512 thr = 8 waves;
// wave w: y-strip sy=(w>>2)*4, co base=(w&3)*16; lane owns ONE pixel and 16
// c_out; per (tap,ci) one ds_read_b32 in the measured-conflict-free pitch-24
// pattern + 16 FMA from SGPR-broadcast weights (wave-uniform s_load).
// ONE addition: staging loop unrolled x4 so 4 independent global loads are
// in flight above the ds_writes (was 1 -> ~300cy exposed per element round).
__global__ __launch_bounds__(512, 2) void snn_exact_kernel(
    const float* __restrict__ x,    // [T,B,C_IN,H,W]
    const float* __restrict__ wt,   // [9][C_IN][C_OUT]
    const float* __restrict__ bias, // [C_OUT]
    float* __restrict__ out)        // [T,B,C_OUT,H,W]
{
    __shared__ __align__(16) float sx[C_IN][ROWS][RLEN];   // 61440 B

    const int tid  = threadIdx.x;
    const int wid  = __builtin_amdgcn_readfirstlane(tid >> 6); // 0..7 (SGPR)
    const int lane = tid & 63;
    const int y    = lane & 3;          // 0..3 within strip
    const int xcol = lane >> 2;         // 0..15
    const int sy   = (wid >> 2) << 2;   // strip base: 0 or 4
    const int cob  = (wid & 3) << 4;    // wave's co base: 0,16,32,48
    const int b    = blockIdx.z;
    const int gy0  = blockIdx.y * TH;
    const int gx0  = blockIdx.x * TW;

    const float* bp = bias + cob;       // wave-uniform -> SGPR

    float v[16];
#pragma unroll
    for (int o = 0; o < 16; ++o) v[o] = 0.0f;

    for (int t = 0; t < T_STEPS; ++t) {
        __syncthreads();  // prior t's reads done before overwrite
        const float* xsrc = x + ((size_t)(t * BATCH + b) * C_IN) * (HH * WW);
#pragma unroll 4
        for (int e = tid; e < C_IN * ROWS * COLS; e += 512) {
            int ci  = e / (ROWS * COLS);
            int rem = e - ci * (ROWS * COLS);
            int row = rem / COLS;
            int col = rem - row * COLS;
            int gy  = gy0 + row - 1;
            int gx  = gx0 + col - 1;
            float val = 0.0f;
            if ((unsigned)gy < (unsigned)HH && (unsigned)gx < (unsigned)WW)
                val = xsrc[ci * (HH * WW) + gy * WW + gx];
            sx[ci][row][col] = val;
        }
        __syncthreads();

        float acc[16];
#pragma unroll
        for (int o = 0; o < 16; ++o) acc[o] = 0.0f;

// One conv tap: ci 0..63 sequential (exact chain order). One ds_read_b32 per
// ci, 16 FMAs with SGPR-broadcast weights (wave-uniform s_load_dwordx16).
#define TAP(KY, KX)                                                                   \
        {                                                                             \
            const float* wj = wt + ((KY) * 3 + (KX)) * (C_IN * C_OUT) + cob;          \
            _Pragma("unroll 4")                                                       \
            for (int ci = 0; ci < C_IN; ++ci) {                                       \
                const float xv = sx[ci][sy + y + (KY)][xcol + (KX)];                  \
                const float* wp = wj + (ci << 6);                                     \
                _Pragma("unroll")                                                     \
                for (int o = 0; o < 16; ++o)                                          \
                    acc[o] = fmaf(xv, wp[o], acc[o]);                                 \
            }                                                                         \
        }

        TAP(0, 0) TAP(0, 1) TAP(0, 2)
        TAP(1, 0) TAP(1, 1) TAP(1, 2)
        TAP(2, 0) TAP(2, 1) TAP(2, 2)
#undef TAP

        // ---- LIF update (exact f32 op sequence) + spike store ----
        float* obase = out + ((size_t)(t * BATCH + b) * C_OUT + cob) * (HH * WW)
                     + (gy0 + sy + y) * WW + gx0 + xcol;
#pragma unroll
        for (int o = 0; o < 16; ++o) {
            float cb = __fadd_rn(acc[o], bp[o]);                  // conv + bias (SGPR)
            float vt = __fadd_rn(__fmul_rn(v[o], DECAY_F32), cb); // v*DECAY + cb
            bool fire = vt > 1.0f;
            v[o] = fire ? 0.0f : vt;                              // soft reset
            obase[(size_t)o * (HH * WW)] = fire ? 1.0f : 0.0f;
        }
    }
}

extern "C" void kernel_launch(void* const* d_in, const int* in_sizes, int n_in,
                              void* d_out, int out_size, void* d_ws, size_t ws_size,
                              hipStream_t stream) {
    const float* x    = (const float*)d_in[0];
    const float* w    = (const float*)d_in[1];
    const float* bias = (const float*)d_in[2];
    float* out = (float*)d_out;
    float* wt  = (float*)d_ws;   // 9*64*64*4 = 147456 bytes

    hipLaunchKernelGGL(wt_build_kernel, dim3((9 * C_IN * C_OUT + 255) / 256), dim3(256), 0, stream, w, wt);
    hipLaunchKernelGGL(snn_exact_kernel, dim3(WW / TW, HH / TH, BATCH), dim3(512), 0, stream,
                       x, wt, bias, out);
}

// Round 20
// 467.692 us; speedup vs baseline: 2.3441x; 1.0263x over previous
//
#include <hip/hip_runtime.h>

#define T_STEPS 4
#define BATCH   8
#define C_IN    64
#define C_OUT   64
#define HH      128
#define WW      128
#define TH      8           // block tile height (2 wave-strips of 4)
#define TW      16
#define ROWS    (TH + 2)    // 10
#define COLS    18          // staged columns (halo)
#define RLEN    24          // padded row pitch (words) -> measured-conflict-free b32 pattern

// f32 rounding of math.exp(-0.5)
#define DECAY_F32 0.6065306597126334f

// Weight re-layout: w[co][ci][ky][kx] -> wt[j][ci][co], j = ky*3+kx
__global__ void wt_build_kernel(const float* __restrict__ w, float* __restrict__ wt) {
    int tid = blockIdx.x * blockDim.x + threadIdx.x;
    if (tid >= 9 * C_IN * C_OUT) return;
    int co = tid & 63;
    int ci = (tid >> 6) & 63;
    int j  = tid >> 12;
    wt[tid] = w[(co * C_IN + ci) * 9 + j];
}

// Exact replica of the reference f32 arithmetic (probe-verified variant A):
// per output: seq FMA chain over (ky,kx, ci-innermost); cb = acc+bias;
// vt = v*DECAY + cb (separate rounded mul/add); spike = vt>1; soft reset.
//
// Measured-best r12 configuration: 512 thr = 8 waves; wave w: y-strip
// sy=(w>>2)*4, co base=(w&3)*16; lane owns ONE pixel and 16 c_out; per
// (tap,ci) one ds_read_b32 (conflict-free pitch-24 pattern) + 16 FMA from
// SGPR-broadcast weights (wave-uniform s_load). ONE change vs r12: TAP inner
// unroll 4 -> 8 (8 ds_reads batched ahead of 256 issue-cy of FMA -> deeper
// self-cover of LDS latency, half the loop overhead).
__global__ __launch_bounds__(512, 2) void snn_exact_kernel(
    const float* __restrict__ x,    // [T,B,C_IN,H,W]
    const float* __restrict__ wt,   // [9][C_IN][C_OUT]
    const float* __restrict__ bias, // [C_OUT]
    float* __restrict__ out)        // [T,B,C_OUT,H,W]
{
    __shared__ __align__(16) float sx[C_IN][ROWS][RLEN];   // 61440 B

    const int tid  = threadIdx.x;
    const int wid  = __builtin_amdgcn_readfirstlane(tid >> 6); // 0..7 (SGPR)
    const int lane = tid & 63;
    const int y    = lane & 3;          // 0..3 within strip
    const int xcol = lane >> 2;         // 0..15
    const int sy   = (wid >> 2) << 2;   // strip base: 0 or 4
    const int cob  = (wid & 3) << 4;    // wave's co base: 0,16,32,48
    const int b    = blockIdx.z;
    const int gy0  = blockIdx.y * TH;
    const int gx0  = blockIdx.x * TW;

    const float* bp = bias + cob;       // wave-uniform -> SGPR

    float v[16];
#pragma unroll
    for (int o = 0; o < 16; ++o) v[o] = 0.0f;

    for (int t = 0; t < T_STEPS; ++t) {
        __syncthreads();  // prior t's reads done before overwrite
        const float* xsrc = x + ((size_t)(t * BATCH + b) * C_IN) * (HH * WW);
#pragma unroll 4
        for (int e = tid; e < C_IN * ROWS * COLS; e += 512) {
            int ci  = e / (ROWS * COLS);
            int rem = e - ci * (ROWS * COLS);
            int row = rem / COLS;
            int col = rem - row * COLS;
            int gy  = gy0 + row - 1;
            int gx  = gx0 + col - 1;
            float val = 0.0f;
            if ((unsigned)gy < (unsigned)HH && (unsigned)gx < (unsigned)WW)
                val = xsrc[ci * (HH * WW) + gy * WW + gx];
            sx[ci][row][col] = val;
        }
        __syncthreads();

        float acc[16];
#pragma unroll
        for (int o = 0; o < 16; ++o) acc[o] = 0.0f;

// One conv tap: ci 0..63 sequential (exact chain order). One ds_read_b32 per
// ci, 16 FMAs with SGPR-broadcast weights (wave-uniform s_load_dwordx16).
#define TAP(KY, KX)                                                                   \
        {                                                                             \
            const float* wj = wt + ((KY) * 3 + (KX)) * (C_IN * C_OUT) + cob;          \
            _Pragma("unroll 8")                                                       \
            for (int ci = 0; ci < C_IN; ++ci) {                                       \
                const float xv = sx[ci][sy + y + (KY)][xcol + (KX)];                  \
                const float* wp = wj + (ci << 6);                                     \
                _Pragma("unroll")                                                     \
                for (int o = 0; o < 16; ++o)                                          \
                    acc[o] = fmaf(xv, wp[o], acc[o]);                                 \
            }                                                                         \
        }

        TAP(0, 0) TAP(0, 1) TAP(0, 2)
        TAP(1, 0) TAP(1, 1) TAP(1, 2)
        TAP(2, 0) TAP(2, 1) TAP(2, 2)
#undef TAP

        // ---- LIF update (exact f32 op sequence) + spike store ----
        float* obase = out + ((size_t)(t * BATCH + b) * C_OUT + cob) * (HH * WW)
                     + (gy0 + sy + y) * WW + gx0 + xcol;
#pragma unroll
        for (int o = 0; o < 16; ++o) {
            float cb = __fadd_rn(acc[o], bp[o]);                  // conv + bias (SGPR)
            float vt = __fadd_rn(__fmul_rn(v[o], DECAY_F32), cb); // v*DECAY + cb
            bool fire = vt > 1.0f;
            v[o] = fire ? 0.0f : vt;                              // soft reset
            obase[(size_t)o * (HH * WW)] = fire ? 1.0f : 0.0f;
        }
    }
}

extern "C" void kernel_launch(void* const* d_in, const int* in_sizes, int n_in,
                              void* d_out, int out_size, void* d_ws, size_t ws_size,
                              hipStream_t stream) {
    const float* x    = (const float*)d_in[0];
    const float* w    = (const float*)d_in[1];
    const float* bias = (const float*)d_in[2];
    float* out = (float*)d_out;
    float* wt  = (float*)d_ws;   // 9*64*64*4 = 147456 bytes

    hipLaunchKernelGGL(wt_build_kernel, dim3((9 * C_IN * C_OUT + 255) / 256), dim3(256), 0, stream, w, wt);
    hipLaunchKernelGGL(snn_exact_kernel, dim3(WW / TW, HH / TH, BATCH), dim3(512), 0, stream,
                       x, wt, bias, out);
}